// Round 20
// baseline (363.735 us; speedup 1.0000x reference)
//
#include <hip/hip_runtime.h>

// VQ codebook nearest-neighbor: xs [32768,512] f32, W [8192,512] f32
// out[i] = W[argmin_j ||xs_i - W_j||^2]
//
// R20: R19 (i8 dist + transposed partials + fused argmin/fixup/gather)
//      with dist register diet: offA/offB collapsed to base+m*1024 imm
//      offsets (swizzle slot provably m-invariant), srcoff[1]=srcoff[0]+32K
//      -> launch_bounds(256,4): 4 blocks/CU (16 waves) vs 3. Util law
//      predicts 23.5% -> ~30%, dist ~205us.

#define M_TOK 32768
#define N_EMB 8192
#define D_K   512
#define WOFF  2048.0f
#define QMASK 0xFFFFFF80u     // 7 low bits = local col (128-wide tile)
#define BAND  5.5f
#define NT    8               // K-tiles of 64 (i8)
#define SCALE 22.6786f        // 127/5.6
#define M2C   (-2.0f / (SCALE * SCALE))

typedef __attribute__((ext_vector_type(4))) int   i32x4;
typedef unsigned long long u64;
typedef unsigned int u32;

__device__ __forceinline__ void gload16(const void* g, void* l) {
  __builtin_amdgcn_global_load_lds(
      (const __attribute__((address_space(1))) unsigned int*)g,
      (__attribute__((address_space(3))) unsigned int*)l, 16, 0, 0);
}

__device__ __forceinline__ u32 map_f(float f) {   // exact order-preserving
  u32 u = __float_as_uint(f);
  return u ^ ((u & 0x80000000u) ? 0xFFFFFFFFu : 0x80000000u);
}
__device__ __forceinline__ float qval(u32 key) {  // quantized approx value
  return __uint_as_float(key & QMASK) - WOFF;
}
__device__ __forceinline__ int q8(float x) {
  int v = __float2int_rn(x * SCALE);
  return v < -127 ? -127 : (v > 127 ? 127 : v);
}

// ---------------- X: f32 -> i8 ----------------
__global__ __launch_bounds__(256) void quant_x_kernel(const float* __restrict__ src,
                                                      char* __restrict__ dst, int n16) {
  int e = blockIdx.x * 256 + threadIdx.x;
  if (e >= n16) return;
  const float4* s4 = (const float4*)src + (size_t)e * 4;
  char out[16];
  #pragma unroll
  for (int i = 0; i < 4; ++i) {
    float4 v = s4[i];
    out[i * 4 + 0] = (char)q8(v.x);
    out[i * 4 + 1] = (char)q8(v.y);
    out[i * 4 + 2] = (char)q8(v.z);
    out[i * 4 + 3] = (char)q8(v.w);
  }
  ((int4*)dst)[e] = *(const int4*)out;
}

// ---------------- W: quantize + exact ||w||^2 ----------------
__global__ __launch_bounds__(256) void quant_w_kernel(const float* __restrict__ w,
                                                      char* __restrict__ Wq,
                                                      float* __restrict__ wnorm) {
  const int row  = blockIdx.x * 4 + (threadIdx.x >> 6);
  const int lane = threadIdx.x & 63;
  const float4* wr = (const float4*)(w + (size_t)row * D_K);
  float4 v0 = wr[lane * 2], v1 = wr[lane * 2 + 1];
  char out[8];
  out[0] = (char)q8(v0.x); out[1] = (char)q8(v0.y);
  out[2] = (char)q8(v0.z); out[3] = (char)q8(v0.w);
  out[4] = (char)q8(v1.x); out[5] = (char)q8(v1.y);
  out[6] = (char)q8(v1.z); out[7] = (char)q8(v1.w);
  *(int2*)(Wq + (size_t)row * D_K + lane * 8) = *(const int2*)out;
  float s = v0.x*v0.x + v0.y*v0.y + v0.z*v0.z + v0.w*v0.w
          + v1.x*v1.x + v1.y*v1.y + v1.z*v1.z + v1.w*v1.w;
  #pragma unroll
  for (int off = 32; off; off >>= 1) s += __shfl_xor(s, off);
  if (lane == 0) wnorm[row] = s;
}

// ---------------- i8 approx distance + per-block best-2 ----------------
// R13/R19 structure; register-dieted: frag offsets are base + m*1024
// (swizzle slot (rl>>1)&3 is m-invariant since m*16>>1 == 0 mod 4), and
// srcoff[1] = srcoff[0] + 32768 (slot invariant since q*64 == 0 mod 4).
// launch_bounds(256,4) -> 4 blocks/CU.
__global__ __launch_bounds__(256, 4) void dist_mfma_kernel(
    const char* __restrict__ Xq, const char* __restrict__ Wq,
    const float* __restrict__ wnorm, uint2* __restrict__ partials) {
  __shared__ char smem[32768];   // buf b at b*16384: [A 8KB | B 8KB]

  int bid = (int)blockIdx.x;
  const int swz = (bid & 7) * 2048 + (bid >> 3);   // XCD swizzle (16384 % 8 == 0)
  const int rt = swz & 255, ct = swz >> 8;          // rt fast -> B-panel L2-hot
  const int row0 = rt * 128, col0 = ct * 128;

  const int tid  = threadIdx.x;
  const int w    = tid >> 6, lane = tid & 63;
  const int wr   = w >> 1,  wc   = w & 1;           // 2x2 wave grid
  const int g    = lane >> 4, cl = lane & 15;

  const char* gA = Xq + (size_t)row0 * D_K;         // row = 512 B
  const char* gB = Wq + (size_t)col0 * D_K;

  // stage source offset (pre-swizzled); chunk c = tid (q=0), r = c>>2.
  // q=1 offset = +64 rows * 512 B = +32768 (same swizzle slot).
  const int r0 = tid >> 2;
  const int src0 = r0 * 512 + (((tid & 3) ^ ((r0 >> 1) & 3)) * 16);

  // frag read base offsets (m/n collapse to +m*1024 immediates)
  const int rlA = wr * 64 + cl;
  const int offA0 = rlA * 64 + ((g ^ ((rlA >> 1) & 3)) * 16);
  const int rlB = wc * 64 + cl;
  const int offB0 = 8192 + rlB * 64 + ((g ^ ((rlB >> 1) & 3)) * 16);

  #define STG(bo, kt)                                                          \
    { gload16(gA + src0 + (kt) * 64,         smem + (bo) + w * 1024);          \
      gload16(gA + src0 + 32768 + (kt) * 64, smem + (bo) + 4096 + w * 1024);   \
      gload16(gB + src0 + (kt) * 64,         smem + (bo) + 8192 + w * 1024);   \
      gload16(gB + src0 + 32768 + (kt) * 64, smem + (bo) + 12288 + w * 1024); }

  i32x4 acc[4][4];
  #pragma unroll
  for (int i = 0; i < 4; i++)
    #pragma unroll
    for (int j = 0; j < 4; j++) acc[i][j] = (i32x4)(0);

  STG(0, 0);
  __syncthreads();

  for (int t = 0; t < NT; ++t) {
    const int rb = (t & 1) * 16384, sb = rb ^ 16384;
    if (t < NT - 1) STG(sb, t + 1);

    i32x4 a[4], b[4];
    #pragma unroll
    for (int m = 0; m < 4; ++m)
      a[m] = *(const i32x4*)(smem + rb + offA0 + m * 1024);
    #pragma unroll
    for (int n = 0; n < 4; ++n)
      b[n] = *(const i32x4*)(smem + rb + offB0 + n * 1024);

    #pragma unroll
    for (int m = 0; m < 4; ++m)
      #pragma unroll
      for (int n = 0; n < 4; ++n)
        acc[m][n] = __builtin_amdgcn_mfma_i32_16x16x64_i8(a[m], b[n], acc[m][n], 0, 0, 0);

    __syncthreads();   // drains vmcnt (stage landed) + lgkm (buf reads done)
  }
  #undef STG

  // ---- epilogue: u32 keys (quantized bits | 7-bit local col), best-2 ----
  float wnp[4];
  u32 colb[4];
  #pragma unroll
  for (int n = 0; n < 4; ++n) {
    const int colL = wc * 64 + n * 16 + cl;
    wnp[n]  = wnorm[col0 + colL] + WOFF;
    colb[n] = (u32)colL;
  }

  uint2* cmb = (uint2*)smem;

  #pragma unroll
  for (int m = 0; m < 4; ++m) {
    #pragma unroll
    for (int r = 0; r < 4; ++r) {
      float s0 = fmaf((float)acc[m][0][r], M2C, wnp[0]);
      float s1 = fmaf((float)acc[m][1][r], M2C, wnp[1]);
      float s2 = fmaf((float)acc[m][2][r], M2C, wnp[2]);
      float s3 = fmaf((float)acc[m][3][r], M2C, wnp[3]);
      u32 k0 = (__float_as_uint(s0) & QMASK) | colb[0];
      u32 k1 = (__float_as_uint(s1) & QMASK) | colb[1];
      u32 k2 = (__float_as_uint(s2) & QMASK) | colb[2];
      u32 k3 = (__float_as_uint(s3) & QMASK) | colb[3];
      u32 pa = min(k0, k1), pb = max(k0, k1);
      u32 pc = min(k2, k3), pd = max(k2, k3);
      u32 c1 = min(pa, pc);
      u32 c2 = min(max(pa, pc), min(pb, pd));
      #pragma unroll
      for (int off = 1; off < 16; off <<= 1) {
        u32 o1 = __shfl_xor(c1, off), o2 = __shfl_xor(c2, off);
        u32 n1 = min(c1, o1);
        c2 = min(min(c2, o2), max(c1, o1));
        c1 = n1;
      }
      if (cl == 0) cmb[(wr * 64 + m * 16 + g * 4 + r) * 2 + wc] = make_uint2(c1, c2);
    }
  }
  __syncthreads();
  if (tid < 128) {
    uint2 A = cmb[tid * 2], B = cmb[tid * 2 + 1];
    u32 c1 = min(A.x, B.x);
    u32 c2 = min(max(A.x, B.x), min(A.y, B.y));
    partials[(size_t)(row0 + tid) * 64 + ct] = make_uint2(c1, c2);   // [token][block]
  }
}

// ---------------- fused wave-owned argmin + exact fixup + gather (R19-proven) ----------------
__global__ __launch_bounds__(256) void argmin_gather_kernel(
    const uint2* __restrict__ partials, const float* __restrict__ xs,
    const float* __restrict__ w, const float* __restrict__ wnorm,
    float* __restrict__ out) {
  const int t = blockIdx.x * 4 + (threadIdx.x >> 6);
  const int lane = threadIdx.x & 63;

  const uint2 e = partials[(size_t)t * 64 + lane];
  u32 b1 = e.x, b2 = e.y;
  #pragma unroll
  for (int off = 1; off < 64; off <<= 1) {
    u32 o1 = __shfl_xor(b1, off), o2 = __shfl_xor(b2, off);
    u32 n1 = min(b1, o1);
    b2 = min(min(b2, o2), max(b1, o1));
    b1 = n1;
  }
  const int bl = __ffsll(__ballot(e.x == b1)) - 1;
  int idx = bl * 128 + (int)(b1 & 127u);

  const float4* xr = (const float4*)(xs + (size_t)t * D_K);
  const float4 xv0 = xr[lane * 2], xv1 = xr[lane * 2 + 1];

  if (qval(b2) - qval(b1) < BAND) {
    const float thr = qval(b1) + BAND;
    const bool in2 = qval(e.y) <= thr;
    const bool in1 = (qval(e.x) <= thr) && !in2;
    u64 mask1 = __ballot(in1);
    u64 mask2 = __ballot(in2);

    u64 best = ~0ULL;
    #define EXACT_DOT(j)                                                       \
      {                                                                        \
        const float4* wrp = (const float4*)(w + (size_t)(j) * D_K);            \
        float4 w0 = wrp[lane * 2], w1 = wrp[lane * 2 + 1];                     \
        float s = xv0.x*w0.x + xv0.y*w0.y + xv0.z*w0.z + xv0.w*w0.w            \
                + xv1.x*w1.x + xv1.y*w1.y + xv1.z*w1.z + xv1.w*w1.w;           \
        _Pragma("unroll")                                                      \
        for (int off = 32; off; off >>= 1) s += __shfl_xor(s, off);            \
        float score = wnorm[j] - 2.0f * s;                                     \
        u64 k = ((u64)map_f(score) << 32) | (u32)(j);                          \
        best = k < best ? k : best;                                           \
      }

    while (mask1) {
      const int l = __ffsll(mask1) - 1;
      mask1 &= mask1 - 1;
      const u32 key = __shfl(e.x, l);
      const int j = l * 128 + (int)(key & 127u);
      EXACT_DOT(j);
    }
    while (mask2) {
      const int l = __ffsll(mask2) - 1;
      mask2 &= mask2 - 1;
      for (int c = 0; c < 128; ++c) {
        const int j = l * 128 + c;
        EXACT_DOT(j);
      }
    }
    #undef EXACT_DOT
    idx = (int)(best & 0xFFFFFFFFULL);                // wave-uniform
  }

  // gather: out = xs + (W[idx] - xs)  (mimic ref arithmetic)
  const float4* wrp = (const float4*)(w + (size_t)idx * D_K);
  float4 w0 = wrp[lane * 2], w1 = wrp[lane * 2 + 1];
  float4 o0, o1;
  o0.x = xv0.x + (w0.x - xv0.x); o0.y = xv0.y + (w0.y - xv0.y);
  o0.z = xv0.z + (w0.z - xv0.z); o0.w = xv0.w + (w0.w - xv0.w);
  o1.x = xv1.x + (w1.x - xv1.x); o1.y = xv1.y + (w1.y - xv1.y);
  o1.z = xv1.z + (w1.z - xv1.z); o1.w = xv1.w + (w1.w - xv1.w);
  float4* orow = (float4*)(out + (size_t)t * D_K);
  orow[lane * 2]     = o0;
  orow[lane * 2 + 1] = o1;
}

extern "C" void kernel_launch(void* const* d_in, const int* in_sizes, int n_in,
                              void* d_out, int out_size, void* d_ws, size_t ws_size,
                              hipStream_t stream) {
  const float* xs = (const float*)d_in[0];
  const float* w  = (const float*)d_in[1];
  float* out = (float*)d_out;

  // ws layout (~36 MB; ws proven >= 85 MB in R2)
  char* p = (char*)d_ws;
  char*  Xq       = p;                       p += (size_t)M_TOK * D_K;        // 16 MB
  char*  Wq       = p;                       p += (size_t)N_EMB * D_K;        //  4 MB
  float* wnorm    = (float*)p;               p += (size_t)N_EMB * 4;
  uint2* partials = (uint2*)p;                                                // 16 MB

  quant_x_kernel<<<(M_TOK * D_K / 16) / 256, 256, 0, stream>>>(xs, Xq, M_TOK * D_K / 16);
  quant_w_kernel<<<N_EMB / 4, 256, 0, stream>>>(w, Wq, wnorm);
  dist_mfma_kernel<<<(M_TOK / 128) * (N_EMB / 128), 256, 0, stream>>>(Xq, Wq, wnorm, partials);
  argmin_gather_kernel<<<M_TOK / 4, 256, 0, stream>>>(partials, xs, w, wnorm, out);
}

// Round 21
// 338.749 us; speedup vs baseline: 1.0738x; 1.0738x over previous
//
#include <hip/hip_runtime.h>

// VQ codebook nearest-neighbor: xs [32768,512] f32, W [8192,512] f32
// out[i] = W[argmin_j ||xs_i - W_j||^2]
//
// R21 = R19 verbatim (best measured: 355 us). i8 MFMA dist kernel (257-263us,
//      0 bank conflicts) with partials transposed to [token][block], plus
//      fused wave-owned argmin + exact-f32 in-band fixup + gather.
//      R20's register diet (4 blocks/CU) proved occupancy-neutral; reverted.

#define M_TOK 32768
#define N_EMB 8192
#define D_K   512
#define WOFF  2048.0f
#define QMASK 0xFFFFFF80u     // 7 low bits = local col (128-wide tile)
#define BAND  5.5f
#define NT    8               // K-tiles of 64 (i8)
#define SCALE 22.6786f        // 127/5.6
#define M2C   (-2.0f / (SCALE * SCALE))

typedef __attribute__((ext_vector_type(4))) int   i32x4;
typedef unsigned long long u64;
typedef unsigned int u32;

__device__ __forceinline__ void gload16(const void* g, void* l) {
  __builtin_amdgcn_global_load_lds(
      (const __attribute__((address_space(1))) unsigned int*)g,
      (__attribute__((address_space(3))) unsigned int*)l, 16, 0, 0);
}

__device__ __forceinline__ u32 map_f(float f) {   // exact order-preserving
  u32 u = __float_as_uint(f);
  return u ^ ((u & 0x80000000u) ? 0xFFFFFFFFu : 0x80000000u);
}
__device__ __forceinline__ float qval(u32 key) {  // quantized approx value
  return __uint_as_float(key & QMASK) - WOFF;
}
__device__ __forceinline__ int q8(float x) {
  int v = __float2int_rn(x * SCALE);
  return v < -127 ? -127 : (v > 127 ? 127 : v);
}

// ---------------- X: f32 -> i8 ----------------
__global__ __launch_bounds__(256) void quant_x_kernel(const float* __restrict__ src,
                                                      char* __restrict__ dst, int n16) {
  int e = blockIdx.x * 256 + threadIdx.x;
  if (e >= n16) return;
  const float4* s4 = (const float4*)src + (size_t)e * 4;
  char out[16];
  #pragma unroll
  for (int i = 0; i < 4; ++i) {
    float4 v = s4[i];
    out[i * 4 + 0] = (char)q8(v.x);
    out[i * 4 + 1] = (char)q8(v.y);
    out[i * 4 + 2] = (char)q8(v.z);
    out[i * 4 + 3] = (char)q8(v.w);
  }
  ((int4*)dst)[e] = *(const int4*)out;
}

// ---------------- W: quantize + exact ||w||^2 ----------------
__global__ __launch_bounds__(256) void quant_w_kernel(const float* __restrict__ w,
                                                      char* __restrict__ Wq,
                                                      float* __restrict__ wnorm) {
  const int row  = blockIdx.x * 4 + (threadIdx.x >> 6);
  const int lane = threadIdx.x & 63;
  const float4* wr = (const float4*)(w + (size_t)row * D_K);
  float4 v0 = wr[lane * 2], v1 = wr[lane * 2 + 1];
  char out[8];
  out[0] = (char)q8(v0.x); out[1] = (char)q8(v0.y);
  out[2] = (char)q8(v0.z); out[3] = (char)q8(v0.w);
  out[4] = (char)q8(v1.x); out[5] = (char)q8(v1.y);
  out[6] = (char)q8(v1.z); out[7] = (char)q8(v1.w);
  *(int2*)(Wq + (size_t)row * D_K + lane * 8) = *(const int2*)out;
  float s = v0.x*v0.x + v0.y*v0.y + v0.z*v0.z + v0.w*v0.w
          + v1.x*v1.x + v1.y*v1.y + v1.z*v1.z + v1.w*v1.w;
  #pragma unroll
  for (int off = 32; off; off >>= 1) s += __shfl_xor(s, off);
  if (lane == 0) wnorm[row] = s;
}

// ---------------- i8 approx distance + per-block best-2 (R13, unchanged) ----------------
// Output: partials[token][block] (transposed for coalesced tail reads).
__global__ __launch_bounds__(256, 3) void dist_mfma_kernel(
    const char* __restrict__ Xq, const char* __restrict__ Wq,
    const float* __restrict__ wnorm, uint2* __restrict__ partials) {
  __shared__ char smem[32768];   // buf b at b*16384: [A 8KB | B 8KB]

  int bid = (int)blockIdx.x;
  const int swz = (bid & 7) * 2048 + (bid >> 3);   // XCD swizzle (16384 % 8 == 0)
  const int rt = swz & 255, ct = swz >> 8;          // rt fast -> B-panel L2-hot
  const int row0 = rt * 128, col0 = ct * 128;

  const int tid  = threadIdx.x;
  const int w    = tid >> 6, lane = tid & 63;
  const int wr   = w >> 1,  wc   = w & 1;           // 2x2 wave grid
  const int g    = lane >> 4, cl = lane & 15;

  const char* gA = Xq + (size_t)row0 * D_K;         // row = 512 B
  const char* gB = Wq + (size_t)col0 * D_K;

  int srcoff[2];
  #pragma unroll
  for (int q = 0; q < 2; ++q) {
    const int c = q * 256 + tid;
    const int r = c >> 2;
    srcoff[q] = r * 512 + (((c & 3) ^ ((r >> 1) & 3)) * 16);
  }

  int offA[4], offB[4];
  #pragma unroll
  for (int m = 0; m < 4; ++m) {
    const int rl = wr * 64 + m * 16 + cl;
    offA[m] = rl * 64 + ((g ^ ((rl >> 1) & 3)) * 16);
  }
  #pragma unroll
  for (int n = 0; n < 4; ++n) {
    const int rl = wc * 64 + n * 16 + cl;
    offB[n] = 8192 + rl * 64 + ((g ^ ((rl >> 1) & 3)) * 16);
  }

  #define STG(bo, kt)                                                          \
    { _Pragma("unroll") for (int q = 0; q < 2; ++q)                            \
        gload16(gA + srcoff[q] + (kt) * 64,                                    \
                smem + (bo) + q * 4096 + w * 1024);                            \
      _Pragma("unroll") for (int q = 0; q < 2; ++q)                            \
        gload16(gB + srcoff[q] + (kt) * 64,                                    \
                smem + (bo) + 8192 + q * 4096 + w * 1024); }

  i32x4 acc[4][4];
  #pragma unroll
  for (int i = 0; i < 4; i++)
    #pragma unroll
    for (int j = 0; j < 4; j++) acc[i][j] = (i32x4)(0);

  STG(0, 0);
  __syncthreads();

  for (int t = 0; t < NT; ++t) {
    const int rb = (t & 1) * 16384, sb = rb ^ 16384;
    if (t < NT - 1) STG(sb, t + 1);

    i32x4 a[4], b[4];
    #pragma unroll
    for (int m = 0; m < 4; ++m) a[m] = *(const i32x4*)(smem + rb + offA[m]);
    #pragma unroll
    for (int n = 0; n < 4; ++n) b[n] = *(const i32x4*)(smem + rb + offB[n]);

    #pragma unroll
    for (int m = 0; m < 4; ++m)
      #pragma unroll
      for (int n = 0; n < 4; ++n)
        acc[m][n] = __builtin_amdgcn_mfma_i32_16x16x64_i8(a[m], b[n], acc[m][n], 0, 0, 0);

    __syncthreads();
  }
  #undef STG

  float wnp[4];
  u32 colb[4];
  #pragma unroll
  for (int n = 0; n < 4; ++n) {
    const int colL = wc * 64 + n * 16 + cl;
    wnp[n]  = wnorm[col0 + colL] + WOFF;
    colb[n] = (u32)colL;
  }

  uint2* cmb = (uint2*)smem;

  #pragma unroll
  for (int m = 0; m < 4; ++m) {
    #pragma unroll
    for (int r = 0; r < 4; ++r) {
      float s0 = fmaf((float)acc[m][0][r], M2C, wnp[0]);
      float s1 = fmaf((float)acc[m][1][r], M2C, wnp[1]);
      float s2 = fmaf((float)acc[m][2][r], M2C, wnp[2]);
      float s3 = fmaf((float)acc[m][3][r], M2C, wnp[3]);
      u32 k0 = (__float_as_uint(s0) & QMASK) | colb[0];
      u32 k1 = (__float_as_uint(s1) & QMASK) | colb[1];
      u32 k2 = (__float_as_uint(s2) & QMASK) | colb[2];
      u32 k3 = (__float_as_uint(s3) & QMASK) | colb[3];
      u32 pa = min(k0, k1), pb = max(k0, k1);
      u32 pc = min(k2, k3), pd = max(k2, k3);
      u32 c1 = min(pa, pc);
      u32 c2 = min(max(pa, pc), min(pb, pd));
      #pragma unroll
      for (int off = 1; off < 16; off <<= 1) {
        u32 o1 = __shfl_xor(c1, off), o2 = __shfl_xor(c2, off);
        u32 n1 = min(c1, o1);
        c2 = min(min(c2, o2), max(c1, o1));
        c1 = n1;
      }
      if (cl == 0) cmb[(wr * 64 + m * 16 + g * 4 + r) * 2 + wc] = make_uint2(c1, c2);
    }
  }
  __syncthreads();
  if (tid < 128) {
    uint2 A = cmb[tid * 2], B = cmb[tid * 2 + 1];
    u32 c1 = min(A.x, B.x);
    u32 c2 = min(max(A.x, B.x), min(A.y, B.y));
    partials[(size_t)(row0 + tid) * 64 + ct] = make_uint2(c1, c2);   // [token][block]
  }
}

// ---------------- fused wave-owned argmin + exact fixup + gather ----------------
__global__ __launch_bounds__(256) void argmin_gather_kernel(
    const uint2* __restrict__ partials, const float* __restrict__ xs,
    const float* __restrict__ w, const float* __restrict__ wnorm,
    float* __restrict__ out) {
  const int t = blockIdx.x * 4 + (threadIdx.x >> 6);
  const int lane = threadIdx.x & 63;

  const uint2 e = partials[(size_t)t * 64 + lane];
  u32 b1 = e.x, b2 = e.y;
  #pragma unroll
  for (int off = 1; off < 64; off <<= 1) {
    u32 o1 = __shfl_xor(b1, off), o2 = __shfl_xor(b2, off);
    u32 n1 = min(b1, o1);
    b2 = min(min(b2, o2), max(b1, o1));
    b1 = n1;
  }
  const int bl = __ffsll(__ballot(e.x == b1)) - 1;
  int idx = bl * 128 + (int)(b1 & 127u);

  const float4* xr = (const float4*)(xs + (size_t)t * D_K);
  const float4 xv0 = xr[lane * 2], xv1 = xr[lane * 2 + 1];

  if (qval(b2) - qval(b1) < BAND) {
    const float thr = qval(b1) + BAND;
    const bool in2 = qval(e.y) <= thr;                // block needs full scan
    const bool in1 = (qval(e.x) <= thr) && !in2;      // single candidate
    u64 mask1 = __ballot(in1);
    u64 mask2 = __ballot(in2);

    u64 best = ~0ULL;
    #define EXACT_DOT(j)                                                       \
      {                                                                        \
        const float4* wrp = (const float4*)(w + (size_t)(j) * D_K);            \
        float4 w0 = wrp[lane * 2], w1 = wrp[lane * 2 + 1];                     \
        float s = xv0.x*w0.x + xv0.y*w0.y + xv0.z*w0.z + xv0.w*w0.w            \
                + xv1.x*w1.x + xv1.y*w1.y + xv1.z*w1.z + xv1.w*w1.w;           \
        _Pragma("unroll")                                                      \
        for (int off = 32; off; off >>= 1) s += __shfl_xor(s, off);            \
        float score = wnorm[j] - 2.0f * s;                                     \
        u64 k = ((u64)map_f(score) << 32) | (u32)(j);                          \
        best = k < best ? k : best;                                           \
      }

    while (mask1) {
      const int l = __ffsll(mask1) - 1;
      mask1 &= mask1 - 1;
      const u32 key = __shfl(e.x, l);
      const int j = l * 128 + (int)(key & 127u);
      EXACT_DOT(j);
    }
    while (mask2) {
      const int l = __ffsll(mask2) - 1;
      mask2 &= mask2 - 1;
      for (int c = 0; c < 128; ++c) {
        const int j = l * 128 + c;
        EXACT_DOT(j);
      }
    }
    #undef EXACT_DOT
    idx = (int)(best & 0xFFFFFFFFULL);                // wave-uniform
  }

  // gather: out = xs + (W[idx] - xs)  (mimic ref arithmetic)
  const float4* wrp = (const float4*)(w + (size_t)idx * D_K);
  float4 w0 = wrp[lane * 2], w1 = wrp[lane * 2 + 1];
  float4 o0, o1;
  o0.x = xv0.x + (w0.x - xv0.x); o0.y = xv0.y + (w0.y - xv0.y);
  o0.z = xv0.z + (w0.z - xv0.z); o0.w = xv0.w + (w0.w - xv0.w);
  o1.x = xv1.x + (w1.x - xv1.x); o1.y = xv1.y + (w1.y - xv1.y);
  o1.z = xv1.z + (w1.z - xv1.z); o1.w = xv1.w + (w1.w - xv1.w);
  float4* orow = (float4*)(out + (size_t)t * D_K);
  orow[lane * 2]     = o0;
  orow[lane * 2 + 1] = o1;
}

extern "C" void kernel_launch(void* const* d_in, const int* in_sizes, int n_in,
                              void* d_out, int out_size, void* d_ws, size_t ws_size,
                              hipStream_t stream) {
  const float* xs = (const float*)d_in[0];
  const float* w  = (const float*)d_in[1];
  float* out = (float*)d_out;

  // ws layout (~36 MB; ws proven >= 85 MB in R2)
  char* p = (char*)d_ws;
  char*  Xq       = p;                       p += (size_t)M_TOK * D_K;        // 16 MB
  char*  Wq       = p;                       p += (size_t)N_EMB * D_K;        //  4 MB
  float* wnorm    = (float*)p;               p += (size_t)N_EMB * 4;
  uint2* partials = (uint2*)p;                                                // 16 MB

  quant_x_kernel<<<(M_TOK * D_K / 16) / 256, 256, 0, stream>>>(xs, Xq, M_TOK * D_K / 16);
  quant_w_kernel<<<N_EMB / 4, 256, 0, stream>>>(w, Wq, wnorm);
  dist_mfma_kernel<<<(M_TOK / 128) * (N_EMB / 128), 256, 0, stream>>>(Xq, Wq, wnorm, partials);
  argmin_gather_kernel<<<M_TOK / 4, 256, 0, stream>>>(partials, xs, w, wnorm, out);
}